// Round 7
// baseline (1640.764 us; speedup 1.0000x reference)
//
#include <hip/hip_runtime.h>
#include <hip/hip_bf16.h>
#include <math.h>

#define DIM 384
#define HEADS 12
#define HD 32
#define MLP_H 1536
#define BATCH 8
#define N1 256
#define N2 257
#define QP 1152          // fused qkv row pitch (shorts)
#define SCALE 0.17677669529663687f
#define TIME_SCALE 18.0f

typedef __attribute__((ext_vector_type(8))) short frag8;
typedef __attribute__((ext_vector_type(4))) float f32x4;

__device__ inline short f2bf(float x) {
    __hip_bfloat16 h = __float2bfloat16(x);
    short s;
    __builtin_memcpy(&s, &h, 2);
    return s;
}
__device__ inline float bf2f(short s) {
    unsigned u = ((unsigned)(unsigned short)s) << 16;
    float f;
    __builtin_memcpy(&f, &u, 4);
    return f;
}

// ------------------------------------------------------------------
// merged weight conversion: 6 fp32->bf16 segments in one launch.
// ------------------------------------------------------------------
__global__ __launch_bounds__(256) void conv6_kernel(
        const float* __restrict__ p0, short* __restrict__ q0, int n0,
        const float* __restrict__ p1, short* __restrict__ q1, int n1,
        const float* __restrict__ p2, short* __restrict__ q2, int n2,
        const float* __restrict__ p3, short* __restrict__ q3, int n3,
        const float* __restrict__ p4, short* __restrict__ q4, int n4,
        const float* __restrict__ p5, short* __restrict__ q5, int n5) {
    (void)n5;
    int blk = blockIdx.x;
    int b0 = n0 >> 10, b1 = n1 >> 10, b2 = n2 >> 10, b3 = n3 >> 10, b4 = n4 >> 10;
    const float* in; short* out;
    if (blk < b0)              { in = p0; out = q0; }
    else if ((blk -= b0) < b1) { in = p1; out = q1; }
    else if ((blk -= b1) < b2) { in = p2; out = q2; }
    else if ((blk -= b2) < b3) { in = p3; out = q3; }
    else if ((blk -= b3) < b4) { in = p4; out = q4; }
    else { blk -= b4;            in = p5; out = q5; }
    int i = blk * 1024 + threadIdx.x * 4;
    float4 v = *(const float4*)(in + i);
    out[i]     = f2bf(v.x);
    out[i + 1] = f2bf(v.y);
    out[i + 2] = f2bf(v.z);
    out[i + 3] = f2bf(v.w);
}

// gather-convert: per layer pack [wq;wk;wv] -> (L,1152,384) bf16
__global__ __launch_bounds__(256) void conv_qkv_kernel(
        const float* __restrict__ wq, const float* __restrict__ wk,
        const float* __restrict__ wv, short* __restrict__ out, int L) {
    size_t idx = ((size_t)blockIdx.x * 256 + threadIdx.x) * 4;
    size_t total = (size_t)L * QP * DIM;
    if (idx >= total) return;
    size_t k = idx % DIM;
    size_t row = idx / DIM;
    size_t r = row % QP;
    size_t l = row / QP;
    int which = (int)(r / DIM);
    int rr = (int)(r % DIM);
    const float* src = ((which == 0) ? wq : (which == 1) ? wk : wv)
                     + (l * DIM + rr) * DIM + k;
    float4 v = *(const float4*)src;
    out[idx]     = f2bf(v.x);
    out[idx + 1] = f2bf(v.y);
    out[idx + 2] = f2bf(v.z);
    out[idx + 3] = f2bf(v.w);
}

// ------------------------------------------------------------------
// rel bias -> bf16.  v2 (verified R3/R4): hw sin/cos + MFMA proj.
// ------------------------------------------------------------------
__global__ __launch_bounds__(256) void rel_kernel(
        const float* __restrict__ x0, const float* __restrict__ w1d,
        const float* __restrict__ b1d, const float* __restrict__ wp,
        const float* __restrict__ bp, short* __restrict__ rel) {
    __shared__ float sw1[8];
    __shared__ float sb1s[1];
    __shared__ short scr[4][64][40];   // per-wave emb, then out (aliased)
    int tid = threadIdx.x;
    int w = tid >> 6, lane = tid & 63;
    int n = lane & 15, quad = lane >> 4;
    if (tid < 8) sw1[tid] = w1d[tid];
    if (tid == 0) sb1s[0] = b1d[0];

    frag8 wb0, wb1;
    #pragma unroll
    for (int e = 0; e < 8; e++) {
        wb0[e] = f2bf(wp[n * 32 + quad * 8 + e]);
        wb1[e] = f2bf(wp[(n + 16) * 32 + quad * 8 + e]);
    }
    float bp0 = bp[n], bp1 = bp[n + 16];
    __syncthreads();
    float sb1 = sb1s[0];

    int gbase = blockIdx.x * 256 + w * 64;
    int gid = gbase + lane;
    int j  = gid & (N1 - 1);
    int bi = gid >> 8;
    int i  = bi & (N1 - 1);
    int b  = bi >> 8;

    const float* pi = x0 + (size_t)(b * N1 + i) * 4;
    const float* pj = x0 + (size_t)(b * N1 + j) * 4;
    float dx = pi[0] - pj[0], dy = pi[1] - pj[1], dz = pi[2] - pj[2];
    float dt = pi[3] - pj[3] * TIME_SCALE;
    float dx2 = dx * dx, dy2 = dy * dy, dz2 = dz * dz, dt2 = dt * dt;
    float ds2 = dx2 + dy2 + dz2 - dt2;
    float d = copysignf(sqrtf(fabsf(ds2)), ds2);
    d += dx * sw1[0] + dy * sw1[1] + dz * sw1[2] + dt * sw1[3]
       + dx2 * sw1[4] + dy2 * sw1[5] + dz2 * sw1[6] + dt2 * sw1[7] + sb1;
    d = fminf(fmaxf(d, -4.f), 4.f) * 1024.f;

    const float freq[16] = {
        1.0f, 0.56234132519f, 0.31622776602f, 0.17782794100f,
        0.1f, 0.056234132519f, 0.031622776602f, 0.017782794100f,
        0.01f, 0.0056234132519f, 0.0031622776602f, 0.0017782794100f,
        0.001f, 0.00056234132519f, 0.00031622776602f, 0.00017782794100f};
    #pragma unroll
    for (int k = 0; k < 16; k++) {
        float rev = d * freq[k] * 0.15915494309189535f;
        rev = rev - floorf(rev);
        float s = __builtin_amdgcn_sinf(rev);
        float c = __builtin_amdgcn_cosf(rev);
        scr[w][lane][k]      = f2bf(s);
        scr[w][lane][16 + k] = f2bf(c);
    }

    #pragma unroll
    for (int g16 = 0; g16 < 4; g16++) {
        frag8 ea = *(const frag8*)&scr[w][g16 * 16 + n][quad * 8];
        f32x4 z = {0.f, 0.f, 0.f, 0.f};
        f32x4 s0 = __builtin_amdgcn_mfma_f32_16x16x32_bf16(ea, wb0, z, 0, 0, 0);
        f32x4 s1 = __builtin_amdgcn_mfma_f32_16x16x32_bf16(ea, wb1, z, 0, 0, 0);
        #pragma unroll
        for (int r = 0; r < 4; r++) {
            scr[w][g16 * 16 + quad * 4 + r][n]      = f2bf(s0[r] + bp0);
            scr[w][g16 * 16 + quad * 4 + r][n + 16] = f2bf(s1[r] + bp1);
        }
    }

    short* dst = rel + (size_t)gbase * HD;
    #pragma unroll
    for (int s = 0; s < 4; s++) {
        frag8 v = *(const frag8*)&scr[w][s * 16 + (lane >> 2)][(lane & 3) * 8];
        *(frag8*)(dst + s * 512 + lane * 8) = v;
    }
}

// ------------------------------------------------------------------
// rel score precompute (layer 0): RS[b][h][i][j] = SCALE * q . rel
// ------------------------------------------------------------------
__global__ __launch_bounds__(256) void rel_score_kernel(
        const short* __restrict__ qkv, const short* __restrict__ relb,
        short* __restrict__ rs) {
    int tid = threadIdx.x;
    int w = tid >> 6, lane = tid & 63;
    int n = lane & 15, quad = lane >> 4;
    int i = blockIdx.x * 4 + w;          // 0..255
    int b = blockIdx.y;

    const frag8 fz = {0, 0, 0, 0, 0, 0, 0, 0};
    frag8 qa = fz;
    if (n < HEADS)
        qa = *(const frag8*)(qkv + ((size_t)(b * N1) + i) * QP + n * HD + quad * 8);

    const short* relrow = relb + (((size_t)(b * N1) + i) * N1) * HD;
    const f32x4 z = {0.f, 0.f, 0.f, 0.f};

    #pragma unroll 4
    for (int jt = 0; jt < 16; jt++) {
        frag8 rb = *(const frag8*)(relrow + (size_t)(jt * 16 + n) * HD + quad * 8);
        f32x4 s = __builtin_amdgcn_mfma_f32_16x16x32_bf16(qa, rb, z, 0, 0, 0);
        #pragma unroll
        for (int r = 0; r < 4; r++) {
            int h = quad * 4 + r;
            if (h < HEADS)
                rs[((size_t)(b * HEADS + h) * N1 + i) * N1 + jt * 16 + n] =
                    f2bf(s[r] * SCALE);
        }
    }
}

// ------------------------------------------------------------------
// rel PV contraction (layer 0)
// ------------------------------------------------------------------
__global__ __launch_bounds__(256) void rel_pv_kernel(
        const short* __restrict__ pglob, const short* __restrict__ relb,
        const float* __restrict__ omain, short* __restrict__ ob) {
    __shared__ short vt[4][2][2][64][8];   // [wave][parity][ctile][x][e]  16 KB
    int tid = threadIdx.x;
    int w = tid >> 6, lane = tid & 63;
    int n = lane & 15, quad = lane >> 4;
    int i = blockIdx.x * 4 + w;
    int b = blockIdx.y;
    size_t rowB = (size_t)(b * N1);

    const frag8 fz = {0, 0, 0, 0, 0, 0, 0, 0};
    f32x4 oa0 = {0.f, 0.f, 0.f, 0.f}, oa1 = {0.f, 0.f, 0.f, 0.f};
    const short* relrow = relb + ((rowB + i) * (size_t)N1) * HD;
    const short* prow = pglob + ((size_t)(b * HEADS + (n < HEADS ? n : 0)) * N1 + i) * N1;
    bool hval = (n < HEADS);

    int jr = lane & 31;
    int cb = (lane >> 5) * 16;

    #pragma unroll 2
    for (int kk = 0; kk < 8; kk++) {
        int par = kk & 1;
        const short* rr = relrow + (size_t)(kk * 32 + jr) * HD + cb;
        frag8 rv0 = *(const frag8*)rr;
        frag8 rv1 = *(const frag8*)(rr + 8);
        #pragma unroll
        for (int e = 0; e < 8; e++) {
            int c0 = cb + e, c1 = cb + 8 + e;
            vt[w][par][c0 >> 4][(jr >> 3) * 16 + (c0 & 15)][jr & 7] = rv0[e];
            vt[w][par][c1 >> 4][(jr >> 3) * 16 + (c1 & 15)][jr & 7] = rv1[e];
        }
        frag8 pa = fz;
        if (hval) pa = *(const frag8*)(prow + kk * 32 + quad * 8);
        frag8 b0 = *(const frag8*)&vt[w][par][0][lane][0];
        frag8 b1 = *(const frag8*)&vt[w][par][1][lane][0];
        oa0 = __builtin_amdgcn_mfma_f32_16x16x32_bf16(pa, b0, oa0, 0, 0, 0);
        oa1 = __builtin_amdgcn_mfma_f32_16x16x32_bf16(pa, b1, oa1, 0, 0, 0);
    }

    #pragma unroll
    for (int r = 0; r < 4; r++) {
        int h = quad * 4 + r;
        if (h < HEADS) {
            size_t o0 = (rowB + i) * DIM + h * HD + n;
            ob[o0]      = f2bf(omain[o0]      + oa0[r]);
            ob[o0 + 16] = f2bf(omain[o0 + 16] + oa1[r]);
        }
    }
}

// ------------------------------------------------------------------
// LayerNorm: fp32 in -> bf16 out
// ------------------------------------------------------------------
__global__ __launch_bounds__(128) void ln_kernel(
        const float* __restrict__ x, const float* __restrict__ g,
        const float* __restrict__ b, short* __restrict__ y) {
    int r = blockIdx.x;
    int t = threadIdx.x;
    const float* xr = x + (size_t)r * DIM;
    float v0 = xr[t], v1 = xr[t + 128], v2 = xr[t + 256];
    __shared__ float redm[2], redv[2];
    float s = v0 + v1 + v2;
    for (int o = 32; o; o >>= 1) s += __shfl_down(s, o, 64);
    int lane = t & 63, wid = t >> 6;
    if (!lane) redm[wid] = s;
    __syncthreads();
    float mean = (redm[0] + redm[1]) * (1.f / DIM);
    float d0 = v0 - mean, d1 = v1 - mean, d2 = v2 - mean;
    float s2 = d0 * d0 + d1 * d1 + d2 * d2;
    for (int o = 32; o; o >>= 1) s2 += __shfl_down(s2, o, 64);
    if (!lane) redv[wid] = s2;
    __syncthreads();
    float var = (redv[0] + redv[1]) * (1.f / DIM);
    float rs = rsqrtf(var + 1e-5f);
    short* yr = y + (size_t)r * DIM;
    yr[t]       = f2bf(d0 * rs * g[t]       + b[t]);
    yr[t + 128] = f2bf(d1 * rs * g[t + 128] + b[t + 128]);
    yr[t + 256] = f2bf(d2 * rs * g[t + 256] + b[t + 256]);
}

// ------------------------------------------------------------------
// bf16 MFMA GEMM v4: 512 thr (8 waves), BK=128, split-K wave groups
// + SoA LDS reduce.  K==384 fast path: ALL 3 iterations' global
// loads pre-issued into registers at kernel start (removes serial
// load-latency chain; 48 of 64 GEMMs have K=384).  K!=384 keeps the
// verified rolling depth-1 prefetch.
// mode 0: ->bf16 Cb. mode 1: bias+GELU ->bf16 Cb.
// mode 2: bias + resid (+gate) ->fp32 Cf.
// ------------------------------------------------------------------
__global__ __launch_bounds__(512) void gemm_bf16_kernel(
        const short* __restrict__ A, const short* __restrict__ W,
        const float* __restrict__ bias, const float* __restrict__ resid,
        const float* __restrict__ gvec, float* __restrict__ Cf,
        short* __restrict__ Cb, int M, int Np, int K, int mode) {
    __shared__ short As2[2][2][4][64][8];   // [kh][ks][q][row][j]  16 KB
    __shared__ short Bs2[2][2][4][64][8];   // 16 KB
    int tid = threadIdx.x;
    int w = tid >> 6, lane = tid & 63;
    int nlo = lane & 15, quad = lane >> 4;
    int g = w >> 2, wl = w & 3;
    int wm = wl >> 1, wn = wl & 1;
    int n0 = blockIdx.x * 64, m0 = blockIdx.y * 64;

    f32x4 acc00 = {0.f, 0.f, 0.f, 0.f}, acc01 = {0.f, 0.f, 0.f, 0.f};
    f32x4 acc10 = {0.f, 0.f, 0.f, 0.f}, acc11 = {0.f, 0.f, 0.f, 0.f};

    int oct16 = tid & 15, rbase = tid >> 4;     // rows rbase, rbase+32
    int kh_s = oct16 >> 3, oo = oct16 & 7, ks_s = oo >> 2, q_s = oo & 3;
    const frag8 fz = {0, 0, 0, 0, 0, 0, 0, 0};
    int gm0 = m0 + rbase, gm1 = m0 + rbase + 32;

    if (K == 384) {
        // ---- fast path: pre-issue all 3 iterations' loads ----
        frag8 la0[3], la1[3], lb0[3], lb1[3];
        #pragma unroll
        for (int it = 0; it < 3; it++) {
            int kk = it * 128 + oct16 * 8;
            la0[it] = fz; la1[it] = fz;
            if (gm0 < M) la0[it] = *(const frag8*)(A + (size_t)gm0 * 384 + kk);
            if (gm1 < M) la1[it] = *(const frag8*)(A + (size_t)gm1 * 384 + kk);
            lb0[it] = *(const frag8*)(W + (size_t)(n0 + rbase) * 384 + kk);
            lb1[it] = *(const frag8*)(W + (size_t)(n0 + rbase + 32) * 384 + kk);
        }
        #pragma unroll
        for (int it = 0; it < 3; it++) {
            *(frag8*)&As2[kh_s][ks_s][q_s][rbase][0]      = la0[it];
            *(frag8*)&As2[kh_s][ks_s][q_s][rbase + 32][0] = la1[it];
            *(frag8*)&Bs2[kh_s][ks_s][q_s][rbase][0]      = lb0[it];
            *(frag8*)&Bs2[kh_s][ks_s][q_s][rbase + 32][0] = lb1[it];
            __syncthreads();
            #pragma unroll
            for (int ks = 0; ks < 2; ks++) {
                frag8 a0 = *(const frag8*)&As2[g][ks][quad][wm * 32 + nlo][0];
                frag8 a1 = *(const frag8*)&As2[g][ks][quad][wm * 32 + 16 + nlo][0];
                frag8 b0 = *(const frag8*)&Bs2[g][ks][quad][wn * 32 + nlo][0];
                frag8 b1 = *(const frag8*)&Bs2[g][ks][quad][wn * 32 + 16 + nlo][0];
                acc00 = __builtin_amdgcn_mfma_f32_16x16x32_bf16(a0, b0, acc00, 0, 0, 0);
                acc01 = __builtin_amdgcn_mfma_f32_16x16x32_bf16(a0, b1, acc01, 0, 0, 0);
                acc10 = __builtin_amdgcn_mfma_f32_16x16x32_bf16(a1, b0, acc10, 0, 0, 0);
                acc11 = __builtin_amdgcn_mfma_f32_16x16x32_bf16(a1, b1, acc11, 0, 0, 0);
            }
            __syncthreads();
        }
    } else {
        // ---- generic rolling depth-1 prefetch (verified R4) ----
        frag8 pa0 = fz, pa1 = fz, pb0, pb1;
        {   // prefetch k0 = 0
            if (gm0 < M) pa0 = *(const frag8*)(A + (size_t)gm0 * K + oct16 * 8);
            if (gm1 < M) pa1 = *(const frag8*)(A + (size_t)gm1 * K + oct16 * 8);
            pb0 = *(const frag8*)(W + (size_t)(n0 + rbase) * K + oct16 * 8);
            pb1 = *(const frag8*)(W + (size_t)(n0 + rbase + 32) * K + oct16 * 8);
        }
        for (int k0 = 0; k0 < K; k0 += 128) {
            *(frag8*)&As2[kh_s][ks_s][q_s][rbase][0]      = pa0;
            *(frag8*)&As2[kh_s][ks_s][q_s][rbase + 32][0] = pa1;
            *(frag8*)&Bs2[kh_s][ks_s][q_s][rbase][0]      = pb0;
            *(frag8*)&Bs2[kh_s][ks_s][q_s][rbase + 32][0] = pb1;
            __syncthreads();
            int kn = k0 + 128;
            if (kn < K) {
                pa0 = fz; pa1 = fz;
                if (gm0 < M) pa0 = *(const frag8*)(A + (size_t)gm0 * K + kn + oct16 * 8);
                if (gm1 < M) pa1 = *(const frag8*)(A + (size_t)gm1 * K + kn + oct16 * 8);
                pb0 = *(const frag8*)(W + (size_t)(n0 + rbase) * K + kn + oct16 * 8);
                pb1 = *(const frag8*)(W + (size_t)(n0 + rbase + 32) * K + kn + oct16 * 8);
            }
            #pragma unroll
            for (int ks = 0; ks < 2; ks++) {
                frag8 a0 = *(const frag8*)&As2[g][ks][quad][wm * 32 + nlo][0];
                frag8 a1 = *(const frag8*)&As2[g][ks][quad][wm * 32 + 16 + nlo][0];
                frag8 b0 = *(const frag8*)&Bs2[g][ks][quad][wn * 32 + nlo][0];
                frag8 b1 = *(const frag8*)&Bs2[g][ks][quad][wn * 32 + 16 + nlo][0];
                acc00 = __builtin_amdgcn_mfma_f32_16x16x32_bf16(a0, b0, acc00, 0, 0, 0);
                acc01 = __builtin_amdgcn_mfma_f32_16x16x32_bf16(a0, b1, acc01, 0, 0, 0);
                acc10 = __builtin_amdgcn_mfma_f32_16x16x32_bf16(a1, b0, acc10, 0, 0, 0);
                acc11 = __builtin_amdgcn_mfma_f32_16x16x32_bf16(a1, b1, acc11, 0, 0, 0);
            }
            __syncthreads();
        }
    }

    // ---- combine wave-group partials (SoA, conflict-free) ----
    f32x4* red4 = (f32x4*)&As2[0][0][0][0][0];   // 4*256 f32x4 = 16 KB
    int roff = wl * 64 + lane;
    if (g == 1) {
        red4[roff]       = acc00;
        red4[256 + roff] = acc01;
        red4[512 + roff] = acc10;
        red4[768 + roff] = acc11;
    }
    __syncthreads();
    if (g == 1) return;
    {
        f32x4 t0 = red4[roff], t1 = red4[256 + roff];
        f32x4 t2 = red4[512 + roff], t3 = red4[768 + roff];
        #pragma unroll
        for (int r = 0; r < 4; r++) {
            acc00[r] += t0[r]; acc01[r] += t1[r];
            acc10[r] += t2[r]; acc11[r] += t3[r];
        }
    }

    // ---- epilogue (group 0 only) ----
    #pragma unroll
    for (int mi = 0; mi < 2; mi++) {
        #pragma unroll
        for (int nf = 0; nf < 2; nf++) {
            f32x4 av = (mi == 0) ? ((nf == 0) ? acc00 : acc01)
                                 : ((nf == 0) ? acc10 : acc11);
            int col = n0 + wn * 32 + nf * 16 + nlo;
            float bcol = (mode >= 1) ? bias[col] : 0.f;
            float gs = 1.f;
            if (mode == 2 && gvec) gs = gvec[col];
            #pragma unroll
            for (int r = 0; r < 4; r++) {
                int row = m0 + wm * 32 + mi * 16 + quad * 4 + r;
                if (row >= M) continue;
                float v = av[r] + bcol;
                if (mode == 1) v = 0.5f * v * (1.f + erff(v * 0.70710678118654752f));
                if (mode == 2) {
                    Cf[(size_t)row * Np + col] = resid[(size_t)row * Np + col] + gs * v;
                } else {
                    Cb[(size_t)row * Np + col] = f2bf(v);
                }
            }
        }
    }
}

// ------------------------------------------------------------------
// MFMA flash attention (no rel) v2: TWO-PASS softmax (verified R6).
// ------------------------------------------------------------------
__global__ __launch_bounds__(256) void attn_mfma_kernel(
        const short* __restrict__ qkv, const float* __restrict__ maskv,
        short* __restrict__ ob, int Nseq) {
    __shared__ short kf[18][64][8];
    __shared__ short vf[9][2][64][8];
    __shared__ short pbuf[4][2][16][40];
    __shared__ float ms[320];

    int tid = threadIdx.x;
    int w = tid >> 6, lane = tid & 63;
    int n = lane & 15, quad = lane >> 4;
    int qg = blockIdx.x, h = blockIdx.y, b = blockIdx.z;
    size_t rowB = (size_t)(b * Nseq);

    for (int j = tid; j < 320; j += 256)
        ms[j] = (j < Nseq) ? maskv[b * Nseq + j] : 0.f;

    {
        int c0 = (tid & 3) * 8;
        for (int j = tid >> 2; j < 288; j += 64) {
            frag8 kk = {0, 0, 0, 0, 0, 0, 0, 0};
            frag8 vv = {0, 0, 0, 0, 0, 0, 0, 0};
            if (j < Nseq) {
                const short* base = qkv + (rowB + j) * QP + h * HD + c0;
                kk = *(const frag8*)(base + 384);
                vv = *(const frag8*)(base + 768);
            }
            *(frag8*)&kf[j >> 4][(c0 >> 3) * 16 + (j & 15)][0] = kk;
            #pragma unroll
            for (int e = 0; e < 8; e++) {
                int c = c0 + e;
                vf[j >> 5][c >> 4][((j & 31) >> 3) * 16 + (c & 15)][j & 7] = vv[e];
            }
        }
    }

    int i0 = qg * 64 + w * 16;
    frag8 qa = {0, 0, 0, 0, 0, 0, 0, 0};
    {
        int i = i0 + n;
        if (i < Nseq) qa = *(const frag8*)(qkv + (rowB + i) * QP + h * HD + quad * 8);
    }
    __syncthreads();

    float msq[4];
    #pragma unroll
    for (int r = 0; r < 4; r++) msq[r] = ms[i0 + quad * 4 + r];

    // ---- pass 1: all 72 scores into registers, local row max ----
    float sv0[36], sv1[36];
    float rmax[4];
    #pragma unroll
    for (int r = 0; r < 4; r++) rmax[r] = -3.0e38f;

    #pragma unroll
    for (int jb = 0; jb < 9; jb++) {
        frag8 kb0 = *(const frag8*)&kf[2 * jb][lane][0];
        frag8 kb1 = *(const frag8*)&kf[2 * jb + 1][lane][0];
        f32x4 z = {0.f, 0.f, 0.f, 0.f};
        f32x4 s0 = __builtin_amdgcn_mfma_f32_16x16x32_bf16(qa, kb0, z, 0, 0, 0);
        f32x4 s1 = __builtin_amdgcn_mfma_f32_16x16x32_bf16(qa, kb1, z, 0, 0, 0);

        int j0 = jb * 32 + n;
        int j1 = j0 + 16;
        float mj0 = ms[j0], mj1 = ms[j1];
        float pad0 = (j0 < Nseq) ? 0.f : -1e9f;
        float pad1 = (j1 < Nseq) ? 0.f : -1e9f;

        #pragma unroll
        for (int r = 0; r < 4; r++) {
            float mi = msq[r];
            float b0 = ((fmaxf(mi, mj0) < 0.f) ? 0.f : fminf(mi, mj0)) + pad0;
            float b1 = ((fmaxf(mi, mj1) < 0.f) ? 0.f : fminf(mi, mj1)) + pad1;
            float v0 = s0[r] * SCALE + b0;
            float v1 = s1[r] * SCALE + b1;
            sv0[jb * 4 + r] = v0;
            sv1[jb * 4 + r] = v1;
            rmax[r] = fmaxf(rmax[r], fmaxf(v0, v1));
        }
    }
    #pragma unroll
    for (int r = 0; r < 4; r++) {
        float rm = rmax[r];
        rm = fmaxf(rm, __shfl_xor(rm, 1));
        rm = fmaxf(rm, __shfl_xor(rm, 2));
        rm = fmaxf(rm, __shfl_xor(rm, 4));
        rm = fmaxf(rm, __shfl_xor(rm, 8));
        rmax[r] = rm;
    }

    // ---- exp + row sum ----
    float lsum[4] = {0.f, 0.f, 0.f, 0.f};
    #pragma unroll
    for (int jb = 0; jb < 9; jb++) {
        #pragma unroll
        for (int r = 0; r < 4; r++) {
            float p0 = __expf(sv0[jb * 4 + r] - rmax[r]);
            float p1 = __expf(sv1[jb * 4 + r] - rmax[r]);
            sv0[jb * 4 + r] = p0;
            sv1[jb * 4 + r] = p1;
            lsum[r] += p0 + p1;
        }
    }
    float invl[4];
    #pragma unroll
    for (int r = 0; r < 4; r++) {
        float ls = lsum[r];
        ls += __shfl_xor(ls, 1);
        ls += __shfl_xor(ls, 2);
        ls += __shfl_xor(ls, 4);
        ls += __shfl_xor(ls, 8);
        invl[r] = 1.f / ls;
    }

    // ---- pass 2: normalized P -> LDS, PV MFMA ----
    f32x4 oacc0 = {0.f, 0.f, 0.f, 0.f}, oacc1 = {0.f, 0.f, 0.f, 0.f};
    #pragma unroll
    for (int jb = 0; jb < 9; jb++) {
        int par = jb & 1;
        #pragma unroll
        for (int r = 0; r < 4; r++) {
            pbuf[w][par][quad * 4 + r][n]      = f2bf(sv0[jb * 4 + r] * invl[r]);
            pbuf[w][par][quad * 4 + r][n + 16] = f2bf(sv1[jb * 4 + r] * invl[r]);
        }
        frag8 pa = *(const frag8*)&pbuf[w][par][n][quad * 8];
        frag8 vb0 = *(const frag8*)&vf[jb][0][lane][0];
        frag8 vb1 = *(const frag8*)&vf[jb][1][lane][0];
        oacc0 = __builtin_amdgcn_mfma_f32_16x16x32_bf16(pa, vb0, oacc0, 0, 0, 0);
        oacc1 = __builtin_amdgcn_mfma_f32_16x16x32_bf16(pa, vb1, oacc1, 0, 0, 0);
    }

    #pragma unroll
    for (int r = 0; r < 4; r++) {
        int i = i0 + quad * 4 + r;
        if (i < Nseq) {
            ob[(rowB + i) * DIM + h * HD + n]      = f2bf(oacc0[r]);
            ob[(rowB + i) * DIM + h * HD + 16 + n] = f2bf(oacc1[r]);
        }
    }
}

// ------------------------------------------------------------------
// MFMA flash attention WITH rel bias (layer 0).  Two-pass softmax,
// writes normalized P in-place to rs, main PV to f32 omain.
// ------------------------------------------------------------------
__global__ __launch_bounds__(128) void attn_rel_mfma_kernel(
        const short* __restrict__ qkv, short* __restrict__ rs,
        const float* __restrict__ maskv, float* __restrict__ omain) {
    const int Nseq = N1;
    __shared__ short kf[16][64][8];
    __shared__ short vf[8][2][64][8];
    __shared__ short pbuf[2][2][16][40];
    __shared__ float ms[256];

    int tid = threadIdx.x;
    int w = tid >> 6, lane = tid & 63;
    int n = lane & 15, quad = lane >> 4;
    int qg = blockIdx.x, h = blockIdx.y, b = blockIdx.z;
    size_t rowB = (size_t)(b * Nseq);

    for (int jj = tid; jj < 256; jj += 128) ms[jj] = maskv[b * Nseq + jj];

    {
        int c0 = (tid & 3) * 8;
        for (int j = tid >> 2; j < 256; j += 32) {
            const short* base = qkv + (rowB + j) * QP + h * HD + c0;
            frag8 kk = *(const frag8*)(base + 384);
            frag8 vv = *(const frag8*)(base + 768);
            *(frag8*)&kf[j >> 4][(c0 >> 3) * 16 + (j & 15)][0] = kk;
            #pragma unroll
            for (int e = 0; e < 8; e++) {
                int c = c0 + e;
                vf[j >> 5][c >> 4][((j & 31) >> 3) * 16 + (c & 15)][j & 7] = vv[e];
            }
        }
    }

    int i0 = qg * 32 + w * 16;
    frag8 qa = *(const frag8*)(qkv + (rowB + i0 + n) * QP + h * HD + quad * 8);
    __syncthreads();

    float msq[4];
    short* rsp[4];
    #pragma unroll
    for (int r = 0; r < 4; r++) {
        msq[r] = ms[i0 + quad * 4 + r];
        rsp[r] = rs + ((size_t)(b * HEADS + h) * N1 + (i0 + quad * 4 + r)) * N1;
    }

    float sv0[32], sv1[32];
    float rmax[4];
    #pragma unroll
    for (int r = 0; r < 4; r++) rmax[r] = -3.0e38f;

    #pragma unroll
    for (int jb = 0; jb < 8; jb++) {
        frag8 kb0 = *(const frag8*)&kf[2 * jb][lane][0];
        frag8 kb1 = *(const frag8*)&kf[2 * jb + 1][lane][0];
        f32x4 z = {0.f, 0.f, 0.f, 0.f};
        f32x4 s0 = __builtin_amdgcn_mfma_f32_16x16x32_bf16(qa, kb0, z, 0, 0, 0);
        f32x4 s1 = __builtin_amdgcn_mfma_f32_16x16x32_bf16(qa, kb1, z, 0, 0, 0);
        int j0 = jb * 32 + n;
        int j1 = j0 + 16;
        float mj0 = ms[j0], mj1 = ms[j1];
        #pragma unroll
        for (int r = 0; r < 4; r++) {
            float d0 = bf2f(rsp[r][j0]);
            float d1 = bf2f(rsp[r][j1]);
            float mi = msq[r];
            float b0 = (fmaxf(mi, mj0) < 0.f) ? 0.f : fminf(mi, mj0);
            float b1 = (fmaxf(mi, mj1) < 0.f) ? 0.f : fminf(mi, mj1);
            float v0 = s0[r] * SCALE + d0 + b0;
            float v1 = s1[r] * SCALE + d1 + b1;
            sv0[jb * 4 + r] = v0;
            sv1[jb * 4 + r] = v1;
            rmax[r] = fmaxf(rmax[r], fmaxf(v0, v1));
        }
    }
    #pragma unroll
    for (int r = 0; r < 4; r++) {
        float rm = rmax[r];
        rm = fmaxf(rm, __shfl_xor(rm, 1));
        rm = fmaxf(rm, __shfl_xor(rm, 2));
        rm = fmaxf(rm, __shfl_xor(rm, 4));
        rm = fmaxf(rm, __shfl_xor(rm, 8));
        rmax[r] = rm;
    }

    float lsum[4] = {0.f, 0.f, 0.f, 0.f};
    #pragma unroll
    for (int jb = 0; jb < 8; jb++) {
        #pragma unroll
        for (int r = 0; r < 4; r++) {
            float p0 = __expf(sv0[jb * 4 + r] - rmax[r]);
            float p1 = __expf(sv1[jb * 4 + r] - rmax[r]);
            sv0[jb * 4 + r] = p0;
            sv1[jb * 4 + r] = p1;
            lsum[r] += p0 + p1;
        }
    }
    float invl[4];
    #pragma unroll
    for (int r = 0; r < 4; r++) {
        float ls = lsum[r];
        ls += __shfl_xor(ls, 1);
        ls += __shfl_xor(ls, 2);
        ls += __shfl_xor(ls, 4);
        ls += __shfl_xor(ls, 8);
        invl[r] = 1.f / ls;
    }

    f32x4 oacc0 = {0.f, 0.f, 0.f, 0.f}, oacc1 = {0.f, 0.f, 0.f, 0.f};
    #pragma unroll
    for (int jb = 0; jb < 8; jb++) {
        int par = jb & 1;
        #pragma unroll
        for (int r = 0; r < 4; r++) {
            short h0 = f2bf(sv0[jb * 4 + r] * invl[r]);
            short h1 = f2bf(sv1[jb * 4 + r] * invl[r]);
            pbuf[w][par][quad * 4 + r][n]      = h0;
            pbuf[w][par][quad * 4 + r][n + 16] = h1;
            rsp[r][jb * 32 + n]      = h0;
            rsp[r][jb * 32 + n + 16] = h1;
        }
        frag8 pa = *(const frag8*)&pbuf[w][par][n][quad * 8];
        frag8 vb0 = *(const frag8*)&vf[jb][0][lane][0];
        frag8 vb1 = *(const frag8*)&vf[jb][1][lane][0];
        oacc0 = __builtin_amdgcn_mfma_f32_16x16x32_bf16(pa, vb0, oacc0, 0, 0, 0);
        oacc1 = __builtin_amdgcn_mfma_f32_16x16x32_bf16(pa, vb1, oacc1, 0, 0, 0);
    }

    #pragma unroll
    for (int r = 0; r < 4; r++) {
        int i = i0 + quad * 4 + r;
        omain[(rowB + i) * DIM + h * HD + n]      = oacc0[r];
        omain[(rowB + i) * DIM + h * HD + 16 + n] = oacc1[r];
    }
}

// ------------------------------------------------------------------
__global__ __launch_bounds__(256) void concat_kernel(
        const float* __restrict__ xa, const float* __restrict__ clsw,
        const float* __restrict__ mask, float* __restrict__ xb,
        float* __restrict__ m2) {
    int idx = blockIdx.x * 256 + threadIdx.x;
    const int total = BATCH * N2 * DIM;
    if (idx < total) {
        int c = idx % DIM;
        int tokb = idx / DIM;
        int p = tokb % N2, b = tokb / N2;
        xb[idx] = (p == 0) ? clsw[c] : xa[((size_t)(b * N1) + p - 1) * DIM + c];
    }
    if (idx < BATCH * N2) {
        int p = idx % N2, b = idx / N2;
        m2[idx] = (p == 0) ? 0.f : mask[b * N1 + p - 1];
    }
}

__global__ __launch_bounds__(64) void head_kernel(
        const float* __restrict__ xb, const float* __restrict__ ow,
        const float* __restrict__ obv, float* __restrict__ out) {
    int blk = blockIdx.x;
    int b = blk / 3, o = blk % 3;
    int lane = threadIdx.x;
    const float* xr = xb + (size_t)(b * N2) * DIM;
    const float* wr = ow + o * DIM;
    float s = 0.f;
    for (int c = lane; c < DIM; c += 64) s += xr[c] * wr[c];
    for (int off = 32; off; off >>= 1) s += __shfl_down(s, off, 64);
    if (!lane) out[blk] = s + obv[o];
}

// ------------------------------------------------------------------
extern "C" void kernel_launch(void* const* d_in, const int* in_sizes, int n_in,
                              void* d_out, int out_size, void* d_ws, size_t ws_size,
                              hipStream_t stream) {
    (void)in_sizes; (void)n_in; (void)out_size; (void)ws_size;
    const float* X       = (const float*)d_in[0];
    const float* X0      = (const float*)d_in[1];
    const float* MSK     = (const float*)d_in[2];
    const float* RW1     = (const float*)d_in[3];
    const float* RB1     = (const float*)d_in[4];
    const float* RWP     = (const float*)d_in[5];
    const float* RBP     = (const float*)d_in[6];
    const float* SW_LN1G = (const float*)d_in[7];
    const float* SW_LN1B = (const float*)d_in[8];
    const float* SW_LN2G = (const float*)d_in[9];
    const float* SW_LN2B = (const float*)d_in[10];
    const float* SW_WQ   = (const float*)d_in[11];
    const float* SW_WK   = (const float*)d_in[12];
    const float* SW_WV   = (const float*)d_in[13];
    const float* SW_WO   = (const float*)d_in[14];
    const float* SW_BO   = (const float*)d_in[15];
    const float* SW_W1   = (const float*)d_in[16];
    const float* SW_B1   = (const float*)d_in[17];
    const float* SW_W2   = (const float*)d_in[18];
    const float* SW_B2   = (const float*)d_in[19];
    const float* BL_LN1G = (const float*)d_in[20];
    const float* BL_LN1B = (const float*)d_in[21];
    const float* BL_LN2G = (const float*)d_in[22];
    const float* BL_LN2B = (const float*)d_in[23];
    const float* BL_WQ   = (const float*)d_in[24];
    const float* BL_WK   = (const float*)d_in[25];
    const float* BL_WV   = (const float*)d_in[26];
    const float* BL_WO   = (const float*)d_in[27];
    const float* BL_BO   = (const float*)d_in[28];
    const float* BL_W1   = (const float*)d_in[29];
    const float* BL_B1   = (const float*)d_in[30];
    const float* BL_W2   = (const float*)d_in[31];
    const float* BL_B2   = (const float*)d_in[32];
    const float* BL_G1   = (const float*)d_in[33];
    const float* BL_G2   = (const float*)d_in[34];
    const float* CLSW    = (const float*)d_in[35];
    const float* OUTW    = (const float*)d_in[36];
    const float* OUTB    = (const float*)d_in[37];

    const int T1 = BATCH * N1;   // 2048
    const int T2 = BATCH * N2;   // 2056
    const size_t RELSZ = (size_t)BATCH * N1 * N1 * HD;   // shorts

    short* rel = (short*)d_ws;
    float* xa  = (float*)(rel + RELSZ);
    float* xb  = xa + (size_t)T1 * DIM;
    float* m2  = xb + (size_t)T2 * DIM;
    short* sbase = (short*)(m2 + 2064);
    short* xn   = sbase;
    short* qkv  = xn  + (size_t)T2 * DIM;
    short* ab   = qkv + (size_t)T2 * QP;
    short* hb   = ab  + (size_t)T2 * DIM;
    short* cw_qkv_sw = hb + (size_t)T2 * MLP_H;
    short* cw_qkv_bl = cw_qkv_sw + (size_t)4  * QP * DIM;
    short* cw_wo_sw  = cw_qkv_bl + (size_t)12 * QP * DIM;
    short* cw_wo_bl  = cw_wo_sw  + (size_t)4  * DIM * DIM;
    short* cw_w1_sw  = cw_wo_bl  + (size_t)12 * DIM * DIM;
    short* cw_w1_bl  = cw_w1_sw  + (size_t)4  * MLP_H * DIM;
    short* cw_w2_sw  = cw_w1_bl  + (size_t)12 * MLP_H * DIM;
    short* cw_w2_bl  = cw_w2_sw  + (size_t)4  * DIM * MLP_H;
    short* rs_buf    = cw_w2_bl  + (size_t)12 * DIM * MLP_H;  // [B][H][N1][N1] bf16
    float* omain     = (float*)hb;   // f32 scratch for layer-0 main PV

    // ---- weight conversion ----
    conv_qkv_kernel<<<(4 * QP * DIM / 4 + 255) / 256, 256, 0, stream>>>(SW_WQ, SW_WK, SW_WV, cw_qkv_sw, 4);
    conv_qkv_kernel<<<(12 * QP * DIM / 4 + 255) / 256, 256, 0, stream>>>(BL_WQ, BL_WK, BL_WV, cw_qkv_bl, 12);
    {
        int e0 = 4 * DIM * DIM, e1 = 12 * DIM * DIM;
        int e2 = 4 * MLP_H * DIM, e3 = 12 * MLP_H * DIM;
        int e4 = 4 * DIM * MLP_H, e5 = 12 * DIM * MLP_H;
        int nblk = (e0 + e1 + e2 + e3 + e4 + e5) >> 10;
        conv6_kernel<<<nblk, 256, 0, stream>>>(
            SW_WO, cw_wo_sw, e0, BL_WO, cw_wo_bl, e1,
            SW_W1, cw_w1_sw, e2, BL_W1, cw_w1_bl, e3,
            SW_W2, cw_w2_sw, e4, BL_W2, cw_w2_bl, e5);
    }

    rel_kernel<<<BATCH * N1 * N1 / 256, 256, 0, stream>>>(X0, RW1, RB1, RWP, RBP, rel);
    hipMemcpyAsync(xa, X, sizeof(float) * T1 * DIM, hipMemcpyDeviceToDevice, stream);

    // ---------------- phase 1: sw layers (N=256) ----------------
    dim3 gQ1(QP / 64, T1 / 64);
    dim3 gP1(DIM / 64, T1 / 64);
    dim3 gM1(MLP_H / 64, T1 / 64);
    dim3 gF1(4, HEADS, BATCH);
    dim3 gRel(8, HEADS, BATCH);
    for (int l = 0; l < 4; l++) {
        const short* wqkv = cw_qkv_sw + (size_t)l * QP * DIM;
        const short* wo = cw_wo_sw + (size_t)l * DIM * DIM;
        const short* w1 = cw_w1_sw + (size_t)l * MLP_H * DIM;
        const short* w2 = cw_w2_sw + (size_t)l * DIM * MLP_H;
        const float* bo = SW_BO + (size_t)l * DIM;
        const float* b1 = SW_B1 + (size_t)l * MLP_H;
        const float* b2 = SW_B2 + (size_t)l * DIM;

        ln_kernel<<<T1, 128, 0, stream>>>(xa, SW_LN1G + l * DIM, SW_LN1B + l * DIM, xn);
        gemm_bf16_kernel<<<gQ1, 512, 0, stream>>>(xn, wqkv, nullptr, nullptr, nullptr,
                                                  nullptr, qkv, T1, QP, DIM, 0);
        if (l == 0) {
            rel_score_kernel<<<dim3(N1 / 4, BATCH), 256, 0, stream>>>(qkv, rel, rs_buf);
            attn_rel_mfma_kernel<<<gRel, 128, 0, stream>>>(qkv, rs_buf, MSK, omain);
            rel_pv_kernel<<<dim3(N1 / 4, BATCH), 256, 0, stream>>>(rs_buf, rel, omain, ab);
        } else {
            attn_mfma_kernel<<<gF1, 256, 0, stream>>>(qkv, MSK, ab, N1);
        }
        gemm_bf16_kernel<<<gP1, 512, 0, stream>>>(ab, wo, bo, xa, nullptr,
                                                  xa, nullptr, T1, DIM, DIM, 2);
        ln_kernel<<<T1, 128, 0, stream>>>(xa, SW_LN2G + l * DIM, SW_LN2B + l * DIM, xn);
        gemm_bf16_kernel<<<gM1, 512, 0, stream>>>(xn, w1, b1, nullptr, nullptr,
                                                  nullptr, hb, T1, MLP_H, DIM, 1);
        gemm_bf16_kernel<<<gP1, 512, 0, stream>>>(hb, w2, b2, xa, nullptr,
                                                  xa, nullptr, T1, DIM, MLP_H, 2);
    }

    // ---------------- concat cls ----------------
    concat_kernel<<<(BATCH * N2 * DIM + 255) / 256, 256, 0, stream>>>(xa, CLSW, MSK, xb, m2);

    // ---------------- phase 2: bl layers (N=257) ----------------
    int MB2 = (T2 + 63) / 64;
    dim3 gQ2(QP / 64, MB2);
    dim3 gP2(DIM / 64, MB2);
    dim3 gM2(MLP_H / 64, MB2);
    dim3 gF2(5, HEADS, BATCH);
    for (int l = 0; l < 12; l++) {
        const short* wqkv = cw_qkv_bl + (size_t)l * QP * DIM;
        const short* wo = cw_wo_bl + (size_t)l * DIM * DIM;
        const short* w1 = cw_w1_bl + (size_t)l * MLP_H * DIM;
        const short* w2 = cw_w2_bl + (size_t)l * DIM * MLP_H;
        const float* bo = BL_BO + (size_t)l * DIM;
        const float* b1 = BL_B1 + (size_t)l * MLP_H;
        const float* b2 = BL_B2 + (size_t)l * DIM;
        const float* g1 = BL_G1 + (size_t)l * DIM;
        const float* g2 = BL_G2 + (size_t)l * DIM;

        ln_kernel<<<T2, 128, 0, stream>>>(xb, BL_LN1G + l * DIM, BL_LN1B + l * DIM, xn);
        gemm_bf16_kernel<<<gQ2, 512, 0, stream>>>(xn, wqkv, nullptr, nullptr, nullptr,
                                                  nullptr, qkv, T2, QP, DIM, 0);
        attn_mfma_kernel<<<gF2, 256, 0, stream>>>(qkv, m2, ab, N2);
        gemm_bf16_kernel<<<gP2, 512, 0, stream>>>(ab, wo, bo, xb, g1,
                                                  xb, nullptr, T2, DIM, DIM, 2);
        ln_kernel<<<T2, 128, 0, stream>>>(xb, BL_LN2G + l * DIM, BL_LN2B + l * DIM, xn);
        gemm_bf16_kernel<<<gM2, 512, 0, stream>>>(xn, w1, b1, nullptr, nullptr,
                                                  nullptr, hb, T2, MLP_H, DIM, 1);
        gemm_bf16_kernel<<<gP2, 512, 0, stream>>>(hb, w2, b2, xb, g2,
                                                  xb, nullptr, T2, DIM, MLP_H, 2);
    }

    // ---------------- head ----------------
    head_kernel<<<BATCH * 3, 64, 0, stream>>>(xb, OUTW, OUTB, (float*)d_out);
}

// Round 8
// 1551.766 us; speedup vs baseline: 1.0574x; 1.0574x over previous
//
#include <hip/hip_runtime.h>
#include <hip/hip_bf16.h>
#include <math.h>

#define DIM 384
#define HEADS 12
#define HD 32
#define MLP_H 1536
#define BATCH 8
#define N1 256
#define N2 257
#define QP 1152          // fused qkv row pitch (shorts)
#define SCALE 0.17677669529663687f
#define TIME_SCALE 18.0f

typedef __attribute__((ext_vector_type(8))) short frag8;
typedef __attribute__((ext_vector_type(4))) float f32x4;

__device__ inline short f2bf(float x) {
    __hip_bfloat16 h = __float2bfloat16(x);
    short s;
    __builtin_memcpy(&s, &h, 2);
    return s;
}
__device__ inline float bf2f(short s) {
    unsigned u = ((unsigned)(unsigned short)s) << 16;
    float f;
    __builtin_memcpy(&f, &u, 4);
    return f;
}

// ------------------------------------------------------------------
// merged weight conversion: 6 fp32->bf16 segments in one launch.
// ------------------------------------------------------------------
__global__ __launch_bounds__(256) void conv6_kernel(
        const float* __restrict__ p0, short* __restrict__ q0, int n0,
        const float* __restrict__ p1, short* __restrict__ q1, int n1,
        const float* __restrict__ p2, short* __restrict__ q2, int n2,
        const float* __restrict__ p3, short* __restrict__ q3, int n3,
        const float* __restrict__ p4, short* __restrict__ q4, int n4,
        const float* __restrict__ p5, short* __restrict__ q5, int n5) {
    (void)n5;
    int blk = blockIdx.x;
    int b0 = n0 >> 10, b1 = n1 >> 10, b2 = n2 >> 10, b3 = n3 >> 10, b4 = n4 >> 10;
    const float* in; short* out;
    if (blk < b0)              { in = p0; out = q0; }
    else if ((blk -= b0) < b1) { in = p1; out = q1; }
    else if ((blk -= b1) < b2) { in = p2; out = q2; }
    else if ((blk -= b2) < b3) { in = p3; out = q3; }
    else if ((blk -= b3) < b4) { in = p4; out = q4; }
    else { blk -= b4;            in = p5; out = q5; }
    int i = blk * 1024 + threadIdx.x * 4;
    float4 v = *(const float4*)(in + i);
    out[i]     = f2bf(v.x);
    out[i + 1] = f2bf(v.y);
    out[i + 2] = f2bf(v.z);
    out[i + 3] = f2bf(v.w);
}

// gather-convert: per layer pack [wq;wk;wv] -> (L,1152,384) bf16
__global__ __launch_bounds__(256) void conv_qkv_kernel(
        const float* __restrict__ wq, const float* __restrict__ wk,
        const float* __restrict__ wv, short* __restrict__ out, int L) {
    size_t idx = ((size_t)blockIdx.x * 256 + threadIdx.x) * 4;
    size_t total = (size_t)L * QP * DIM;
    if (idx >= total) return;
    size_t k = idx % DIM;
    size_t row = idx / DIM;
    size_t r = row % QP;
    size_t l = row / QP;
    int which = (int)(r / DIM);
    int rr = (int)(r % DIM);
    const float* src = ((which == 0) ? wq : (which == 1) ? wk : wv)
                     + (l * DIM + rr) * DIM + k;
    float4 v = *(const float4*)src;
    out[idx]     = f2bf(v.x);
    out[idx + 1] = f2bf(v.y);
    out[idx + 2] = f2bf(v.z);
    out[idx + 3] = f2bf(v.w);
}

// ------------------------------------------------------------------
// rel bias -> bf16.  v2 (verified R3/R4): hw sin/cos + MFMA proj.
// ------------------------------------------------------------------
__global__ __launch_bounds__(256) void rel_kernel(
        const float* __restrict__ x0, const float* __restrict__ w1d,
        const float* __restrict__ b1d, const float* __restrict__ wp,
        const float* __restrict__ bp, short* __restrict__ rel) {
    __shared__ float sw1[8];
    __shared__ float sb1s[1];
    __shared__ short scr[4][64][40];   // per-wave emb, then out (aliased)
    int tid = threadIdx.x;
    int w = tid >> 6, lane = tid & 63;
    int n = lane & 15, quad = lane >> 4;
    if (tid < 8) sw1[tid] = w1d[tid];
    if (tid == 0) sb1s[0] = b1d[0];

    frag8 wb0, wb1;
    #pragma unroll
    for (int e = 0; e < 8; e++) {
        wb0[e] = f2bf(wp[n * 32 + quad * 8 + e]);
        wb1[e] = f2bf(wp[(n + 16) * 32 + quad * 8 + e]);
    }
    float bp0 = bp[n], bp1 = bp[n + 16];
    __syncthreads();
    float sb1 = sb1s[0];

    int gbase = blockIdx.x * 256 + w * 64;
    int gid = gbase + lane;
    int j  = gid & (N1 - 1);
    int bi = gid >> 8;
    int i  = bi & (N1 - 1);
    int b  = bi >> 8;

    const float* pi = x0 + (size_t)(b * N1 + i) * 4;
    const float* pj = x0 + (size_t)(b * N1 + j) * 4;
    float dx = pi[0] - pj[0], dy = pi[1] - pj[1], dz = pi[2] - pj[2];
    float dt = pi[3] - pj[3] * TIME_SCALE;
    float dx2 = dx * dx, dy2 = dy * dy, dz2 = dz * dz, dt2 = dt * dt;
    float ds2 = dx2 + dy2 + dz2 - dt2;
    float d = copysignf(sqrtf(fabsf(ds2)), ds2);
    d += dx * sw1[0] + dy * sw1[1] + dz * sw1[2] + dt * sw1[3]
       + dx2 * sw1[4] + dy2 * sw1[5] + dz2 * sw1[6] + dt2 * sw1[7] + sb1;
    d = fminf(fmaxf(d, -4.f), 4.f) * 1024.f;

    const float freq[16] = {
        1.0f, 0.56234132519f, 0.31622776602f, 0.17782794100f,
        0.1f, 0.056234132519f, 0.031622776602f, 0.017782794100f,
        0.01f, 0.0056234132519f, 0.0031622776602f, 0.0017782794100f,
        0.001f, 0.00056234132519f, 0.00031622776602f, 0.00017782794100f};
    #pragma unroll
    for (int k = 0; k < 16; k++) {
        float rev = d * freq[k] * 0.15915494309189535f;
        rev = rev - floorf(rev);
        float s = __builtin_amdgcn_sinf(rev);
        float c = __builtin_amdgcn_cosf(rev);
        scr[w][lane][k]      = f2bf(s);
        scr[w][lane][16 + k] = f2bf(c);
    }

    #pragma unroll
    for (int g16 = 0; g16 < 4; g16++) {
        frag8 ea = *(const frag8*)&scr[w][g16 * 16 + n][quad * 8];
        f32x4 z = {0.f, 0.f, 0.f, 0.f};
        f32x4 s0 = __builtin_amdgcn_mfma_f32_16x16x32_bf16(ea, wb0, z, 0, 0, 0);
        f32x4 s1 = __builtin_amdgcn_mfma_f32_16x16x32_bf16(ea, wb1, z, 0, 0, 0);
        #pragma unroll
        for (int r = 0; r < 4; r++) {
            scr[w][g16 * 16 + quad * 4 + r][n]      = f2bf(s0[r] + bp0);
            scr[w][g16 * 16 + quad * 4 + r][n + 16] = f2bf(s1[r] + bp1);
        }
    }

    short* dst = rel + (size_t)gbase * HD;
    #pragma unroll
    for (int s = 0; s < 4; s++) {
        frag8 v = *(const frag8*)&scr[w][s * 16 + (lane >> 2)][(lane & 3) * 8];
        *(frag8*)(dst + s * 512 + lane * 8) = v;
    }
}

// ------------------------------------------------------------------
// rel score precompute (layer 0): RS[b][h][i][j] = SCALE * q . rel
// ------------------------------------------------------------------
__global__ __launch_bounds__(256) void rel_score_kernel(
        const short* __restrict__ qkv, const short* __restrict__ relb,
        short* __restrict__ rs) {
    int tid = threadIdx.x;
    int w = tid >> 6, lane = tid & 63;
    int n = lane & 15, quad = lane >> 4;
    int i = blockIdx.x * 4 + w;          // 0..255
    int b = blockIdx.y;

    const frag8 fz = {0, 0, 0, 0, 0, 0, 0, 0};
    frag8 qa = fz;
    if (n < HEADS)
        qa = *(const frag8*)(qkv + ((size_t)(b * N1) + i) * QP + n * HD + quad * 8);

    const short* relrow = relb + (((size_t)(b * N1) + i) * N1) * HD;
    const f32x4 z = {0.f, 0.f, 0.f, 0.f};

    #pragma unroll 4
    for (int jt = 0; jt < 16; jt++) {
        frag8 rb = *(const frag8*)(relrow + (size_t)(jt * 16 + n) * HD + quad * 8);
        f32x4 s = __builtin_amdgcn_mfma_f32_16x16x32_bf16(qa, rb, z, 0, 0, 0);
        #pragma unroll
        for (int r = 0; r < 4; r++) {
            int h = quad * 4 + r;
            if (h < HEADS)
                rs[((size_t)(b * HEADS + h) * N1 + i) * N1 + jt * 16 + n] =
                    f2bf(s[r] * SCALE);
        }
    }
}

// ------------------------------------------------------------------
// rel PV contraction (layer 0)
// ------------------------------------------------------------------
__global__ __launch_bounds__(256) void rel_pv_kernel(
        const short* __restrict__ pglob, const short* __restrict__ relb,
        const float* __restrict__ omain, short* __restrict__ ob) {
    __shared__ short vt[4][2][2][64][8];   // [wave][parity][ctile][x][e]  16 KB
    int tid = threadIdx.x;
    int w = tid >> 6, lane = tid & 63;
    int n = lane & 15, quad = lane >> 4;
    int i = blockIdx.x * 4 + w;
    int b = blockIdx.y;
    size_t rowB = (size_t)(b * N1);

    const frag8 fz = {0, 0, 0, 0, 0, 0, 0, 0};
    f32x4 oa0 = {0.f, 0.f, 0.f, 0.f}, oa1 = {0.f, 0.f, 0.f, 0.f};
    const short* relrow = relb + ((rowB + i) * (size_t)N1) * HD;
    const short* prow = pglob + ((size_t)(b * HEADS + (n < HEADS ? n : 0)) * N1 + i) * N1;
    bool hval = (n < HEADS);

    int jr = lane & 31;
    int cb = (lane >> 5) * 16;

    #pragma unroll 2
    for (int kk = 0; kk < 8; kk++) {
        int par = kk & 1;
        const short* rr = relrow + (size_t)(kk * 32 + jr) * HD + cb;
        frag8 rv0 = *(const frag8*)rr;
        frag8 rv1 = *(const frag8*)(rr + 8);
        #pragma unroll
        for (int e = 0; e < 8; e++) {
            int c0 = cb + e, c1 = cb + 8 + e;
            vt[w][par][c0 >> 4][(jr >> 3) * 16 + (c0 & 15)][jr & 7] = rv0[e];
            vt[w][par][c1 >> 4][(jr >> 3) * 16 + (c1 & 15)][jr & 7] = rv1[e];
        }
        frag8 pa = fz;
        if (hval) pa = *(const frag8*)(prow + kk * 32 + quad * 8);
        frag8 b0 = *(const frag8*)&vt[w][par][0][lane][0];
        frag8 b1 = *(const frag8*)&vt[w][par][1][lane][0];
        oa0 = __builtin_amdgcn_mfma_f32_16x16x32_bf16(pa, b0, oa0, 0, 0, 0);
        oa1 = __builtin_amdgcn_mfma_f32_16x16x32_bf16(pa, b1, oa1, 0, 0, 0);
    }

    #pragma unroll
    for (int r = 0; r < 4; r++) {
        int h = quad * 4 + r;
        if (h < HEADS) {
            size_t o0 = (rowB + i) * DIM + h * HD + n;
            ob[o0]      = f2bf(omain[o0]      + oa0[r]);
            ob[o0 + 16] = f2bf(omain[o0 + 16] + oa1[r]);
        }
    }
}

// ------------------------------------------------------------------
// LayerNorm: fp32 in -> bf16 out
// ------------------------------------------------------------------
__global__ __launch_bounds__(128) void ln_kernel(
        const float* __restrict__ x, const float* __restrict__ g,
        const float* __restrict__ b, short* __restrict__ y) {
    int r = blockIdx.x;
    int t = threadIdx.x;
    const float* xr = x + (size_t)r * DIM;
    float v0 = xr[t], v1 = xr[t + 128], v2 = xr[t + 256];
    __shared__ float redm[2], redv[2];
    float s = v0 + v1 + v2;
    for (int o = 32; o; o >>= 1) s += __shfl_down(s, o, 64);
    int lane = t & 63, wid = t >> 6;
    if (!lane) redm[wid] = s;
    __syncthreads();
    float mean = (redm[0] + redm[1]) * (1.f / DIM);
    float d0 = v0 - mean, d1 = v1 - mean, d2 = v2 - mean;
    float s2 = d0 * d0 + d1 * d1 + d2 * d2;
    for (int o = 32; o; o >>= 1) s2 += __shfl_down(s2, o, 64);
    if (!lane) redv[wid] = s2;
    __syncthreads();
    float var = (redv[0] + redv[1]) * (1.f / DIM);
    float rs = rsqrtf(var + 1e-5f);
    short* yr = y + (size_t)r * DIM;
    yr[t]       = f2bf(d0 * rs * g[t]       + b[t]);
    yr[t + 128] = f2bf(d1 * rs * g[t + 128] + b[t + 128]);
    yr[t + 256] = f2bf(d2 * rs * g[t + 256] + b[t + 256]);
}

// ------------------------------------------------------------------
// WIDE-TILE bf16 MFMA GEMM: tile 128(M)x64(N), BK=128, 512 thr,
// 8 waves each owning a 32x32 output quadrant (no split-K groups,
// no reduce epilogue).  Halves barriers/stage-passes per FLOP vs
// the 64x64 kernel.  For N>=1152 GEMMs (QKV, MLP1).
// mode 0: ->bf16 Cb.  mode 1: bias+GELU ->bf16 Cb.
// ------------------------------------------------------------------
__global__ __launch_bounds__(512) void gemm128_bf16_kernel(
        const short* __restrict__ A, const short* __restrict__ W,
        const float* __restrict__ bias, short* __restrict__ Cb,
        int M, int Np, int K, int mode) {
    __shared__ short As[2][2][4][128][8];   // 32 KB  [kh][ks][q][row][8]
    __shared__ short Bs[2][2][4][64][8];    // 16 KB
    int tid = threadIdx.x;
    int w = tid >> 6, lane = tid & 63;
    int nlo = lane & 15, quad = lane >> 4;
    int wm = w >> 1, wn = w & 1;
    int n0 = blockIdx.x * 64, m0 = blockIdx.y * 128;

    f32x4 acc00 = {0.f, 0.f, 0.f, 0.f}, acc01 = {0.f, 0.f, 0.f, 0.f};
    f32x4 acc10 = {0.f, 0.f, 0.f, 0.f}, acc11 = {0.f, 0.f, 0.f, 0.f};

    const frag8 fz = {0, 0, 0, 0, 0, 0, 0, 0};
    int rA = tid >> 2, sA = tid & 3;     // A: 4 stores, slots sA+4u, row rA
    int rB = tid >> 3, sB = tid & 7;     // B: 2 stores, slots sB+8u, row rB
    int gmA = m0 + rA;

    frag8 pa[4], pb[2];
    #pragma unroll
    for (int u = 0; u < 4; u++) {
        int s = sA + u * 4;
        pa[u] = fz;
        if (gmA < M) pa[u] = *(const frag8*)(A + (size_t)gmA * K + s * 8);
    }
    #pragma unroll
    for (int u = 0; u < 2; u++) {
        int s = sB + u * 8;
        pb[u] = *(const frag8*)(W + (size_t)(n0 + rB) * K + s * 8);
    }

    for (int k0 = 0; k0 < K; k0 += 128) {
        #pragma unroll
        for (int u = 0; u < 4; u++) {
            int s = sA + u * 4;
            *(frag8*)&As[s >> 3][(s >> 2) & 1][s & 3][rA][0] = pa[u];
        }
        #pragma unroll
        for (int u = 0; u < 2; u++) {
            int s = sB + u * 8;
            *(frag8*)&Bs[s >> 3][(s >> 2) & 1][s & 3][rB][0] = pb[u];
        }
        __syncthreads();
        int kn = k0 + 128;
        if (kn < K) {
            #pragma unroll
            for (int u = 0; u < 4; u++) {
                int s = sA + u * 4;
                pa[u] = fz;
                if (gmA < M) pa[u] = *(const frag8*)(A + (size_t)gmA * K + kn + s * 8);
            }
            #pragma unroll
            for (int u = 0; u < 2; u++) {
                int s = sB + u * 8;
                pb[u] = *(const frag8*)(W + (size_t)(n0 + rB) * K + kn + s * 8);
            }
        }
        #pragma unroll
        for (int c = 0; c < 4; c++) {
            frag8 a0 = *(const frag8*)&As[c >> 1][c & 1][quad][wm * 32 + nlo][0];
            frag8 a1 = *(const frag8*)&As[c >> 1][c & 1][quad][wm * 32 + 16 + nlo][0];
            frag8 b0 = *(const frag8*)&Bs[c >> 1][c & 1][quad][wn * 32 + nlo][0];
            frag8 b1 = *(const frag8*)&Bs[c >> 1][c & 1][quad][wn * 32 + 16 + nlo][0];
            acc00 = __builtin_amdgcn_mfma_f32_16x16x32_bf16(a0, b0, acc00, 0, 0, 0);
            acc01 = __builtin_amdgcn_mfma_f32_16x16x32_bf16(a0, b1, acc01, 0, 0, 0);
            acc10 = __builtin_amdgcn_mfma_f32_16x16x32_bf16(a1, b0, acc10, 0, 0, 0);
            acc11 = __builtin_amdgcn_mfma_f32_16x16x32_bf16(a1, b1, acc11, 0, 0, 0);
        }
        __syncthreads();
    }

    // ---- epilogue: direct write (no reduce) ----
    #pragma unroll
    for (int mi = 0; mi < 2; mi++) {
        #pragma unroll
        for (int nf = 0; nf < 2; nf++) {
            f32x4 av = (mi == 0) ? ((nf == 0) ? acc00 : acc01)
                                 : ((nf == 0) ? acc10 : acc11);
            int col = n0 + wn * 32 + nf * 16 + nlo;
            float bcol = (mode == 1) ? bias[col] : 0.f;
            #pragma unroll
            for (int r = 0; r < 4; r++) {
                int row = m0 + wm * 32 + mi * 16 + quad * 4 + r;
                if (row >= M) continue;
                float v = av[r] + bcol;
                if (mode == 1) v = 0.5f * v * (1.f + erff(v * 0.70710678118654752f));
                Cb[(size_t)row * Np + col] = f2bf(v);
            }
        }
    }
}

// ------------------------------------------------------------------
// bf16 MFMA GEMM v4 (64x64, verified): for N=384 GEMMs.
// mode 1: bias+GELU ->bf16 Cb.  mode 2: bias+resid(+gate) ->fp32 Cf.
// K==384 fast path pre-issues all loads (neutral, kept from R7).
// ------------------------------------------------------------------
__global__ __launch_bounds__(512) void gemm_bf16_kernel(
        const short* __restrict__ A, const short* __restrict__ W,
        const float* __restrict__ bias, const float* __restrict__ resid,
        const float* __restrict__ gvec, float* __restrict__ Cf,
        short* __restrict__ Cb, int M, int Np, int K, int mode) {
    __shared__ short As2[2][2][4][64][8];   // [kh][ks][q][row][j]  16 KB
    __shared__ short Bs2[2][2][4][64][8];   // 16 KB
    int tid = threadIdx.x;
    int w = tid >> 6, lane = tid & 63;
    int nlo = lane & 15, quad = lane >> 4;
    int g = w >> 2, wl = w & 3;
    int wm = wl >> 1, wn = wl & 1;
    int n0 = blockIdx.x * 64, m0 = blockIdx.y * 64;

    f32x4 acc00 = {0.f, 0.f, 0.f, 0.f}, acc01 = {0.f, 0.f, 0.f, 0.f};
    f32x4 acc10 = {0.f, 0.f, 0.f, 0.f}, acc11 = {0.f, 0.f, 0.f, 0.f};

    int oct16 = tid & 15, rbase = tid >> 4;     // rows rbase, rbase+32
    int kh_s = oct16 >> 3, oo = oct16 & 7, ks_s = oo >> 2, q_s = oo & 3;
    const frag8 fz = {0, 0, 0, 0, 0, 0, 0, 0};
    int gm0 = m0 + rbase, gm1 = m0 + rbase + 32;

    if (K == 384) {
        // ---- fast path: pre-issue all 3 iterations' loads ----
        frag8 la0[3], la1[3], lb0[3], lb1[3];
        #pragma unroll
        for (int it = 0; it < 3; it++) {
            int kk = it * 128 + oct16 * 8;
            la0[it] = fz; la1[it] = fz;
            if (gm0 < M) la0[it] = *(const frag8*)(A + (size_t)gm0 * 384 + kk);
            if (gm1 < M) la1[it] = *(const frag8*)(A + (size_t)gm1 * 384 + kk);
            lb0[it] = *(const frag8*)(W + (size_t)(n0 + rbase) * 384 + kk);
            lb1[it] = *(const frag8*)(W + (size_t)(n0 + rbase + 32) * 384 + kk);
        }
        #pragma unroll
        for (int it = 0; it < 3; it++) {
            *(frag8*)&As2[kh_s][ks_s][q_s][rbase][0]      = la0[it];
            *(frag8*)&As2[kh_s][ks_s][q_s][rbase + 32][0] = la1[it];
            *(frag8*)&Bs2[kh_s][ks_s][q_s][rbase][0]      = lb0[it];
            *(frag8*)&Bs2[kh_s][ks_s][q_s][rbase + 32][0] = lb1[it];
            __syncthreads();
            #pragma unroll
            for (int ks = 0; ks < 2; ks++) {
                frag8 a0 = *(const frag8*)&As2[g][ks][quad][wm * 32 + nlo][0];
                frag8 a1 = *(const frag8*)&As2[g][ks][quad][wm * 32 + 16 + nlo][0];
                frag8 b0 = *(const frag8*)&Bs2[g][ks][quad][wn * 32 + nlo][0];
                frag8 b1 = *(const frag8*)&Bs2[g][ks][quad][wn * 32 + 16 + nlo][0];
                acc00 = __builtin_amdgcn_mfma_f32_16x16x32_bf16(a0, b0, acc00, 0, 0, 0);
                acc01 = __builtin_amdgcn_mfma_f32_16x16x32_bf16(a0, b1, acc01, 0, 0, 0);
                acc10 = __builtin_amdgcn_mfma_f32_16x16x32_bf16(a1, b0, acc10, 0, 0, 0);
                acc11 = __builtin_amdgcn_mfma_f32_16x16x32_bf16(a1, b1, acc11, 0, 0, 0);
            }
            __syncthreads();
        }
    } else {
        // ---- generic rolling depth-1 prefetch (verified R4) ----
        frag8 pa0 = fz, pa1 = fz, pb0, pb1;
        {   // prefetch k0 = 0
            if (gm0 < M) pa0 = *(const frag8*)(A + (size_t)gm0 * K + oct16 * 8);
            if (gm1 < M) pa1 = *(const frag8*)(A + (size_t)gm1 * K + oct16 * 8);
            pb0 = *(const frag8*)(W + (size_t)(n0 + rbase) * K + oct16 * 8);
            pb1 = *(const frag8*)(W + (size_t)(n0 + rbase + 32) * K + oct16 * 8);
        }
        for (int k0 = 0; k0 < K; k0 += 128) {
            *(frag8*)&As2[kh_s][ks_s][q_s][rbase][0]      = pa0;
            *(frag8*)&As2[kh_s][ks_s][q_s][rbase + 32][0] = pa1;
            *(frag8*)&Bs2[kh_s][ks_s][q_s][rbase][0]      = pb0;
            *(frag8*)&Bs2[kh_s][ks_s][q_s][rbase + 32][0] = pb1;
            __syncthreads();
            int kn = k0 + 128;
            if (kn < K) {
                pa0 = fz; pa1 = fz;
                if (gm0 < M) pa0 = *(const frag8*)(A + (size_t)gm0 * K + kn + oct16 * 8);
                if (gm1 < M) pa1 = *(const frag8*)(A + (size_t)gm1 * K + kn + oct16 * 8);
                pb0 = *(const frag8*)(W + (size_t)(n0 + rbase) * K + kn + oct16 * 8);
                pb1 = *(const frag8*)(W + (size_t)(n0 + rbase + 32) * K + kn + oct16 * 8);
            }
            #pragma unroll
            for (int ks = 0; ks < 2; ks++) {
                frag8 a0 = *(const frag8*)&As2[g][ks][quad][wm * 32 + nlo][0];
                frag8 a1 = *(const frag8*)&As2[g][ks][quad][wm * 32 + 16 + nlo][0];
                frag8 b0 = *(const frag8*)&Bs2[g][ks][quad][wn * 32 + nlo][0];
                frag8 b1 = *(const frag8*)&Bs2[g][ks][quad][wn * 32 + 16 + nlo][0];
                acc00 = __builtin_amdgcn_mfma_f32_16x16x32_bf16(a0, b0, acc00, 0, 0, 0);
                acc01 = __builtin_amdgcn_mfma_f32_16x16x32_bf16(a0, b1, acc01, 0, 0, 0);
                acc10 = __builtin_amdgcn_mfma_f32_16x16x32_bf16(a1, b0, acc10, 0, 0, 0);
                acc11 = __builtin_amdgcn_mfma_f32_16x16x32_bf16(a1, b1, acc11, 0, 0, 0);
            }
            __syncthreads();
        }
    }

    // ---- combine wave-group partials (SoA, conflict-free) ----
    f32x4* red4 = (f32x4*)&As2[0][0][0][0][0];   // 4*256 f32x4 = 16 KB
    int roff = wl * 64 + lane;
    if (g == 1) {
        red4[roff]       = acc00;
        red4[256 + roff] = acc01;
        red4[512 + roff] = acc10;
        red4[768 + roff] = acc11;
    }
    __syncthreads();
    if (g == 1) return;
    {
        f32x4 t0 = red4[roff], t1 = red4[256 + roff];
        f32x4 t2 = red4[512 + roff], t3 = red4[768 + roff];
        #pragma unroll
        for (int r = 0; r < 4; r++) {
            acc00[r] += t0[r]; acc01[r] += t1[r];
            acc10[r] += t2[r]; acc11[r] += t3[r];
        }
    }

    // ---- epilogue (group 0 only) ----
    #pragma unroll
    for (int mi = 0; mi < 2; mi++) {
        #pragma unroll
        for (int nf = 0; nf < 2; nf++) {
            f32x4 av = (mi == 0) ? ((nf == 0) ? acc00 : acc01)
                                 : ((nf == 0) ? acc10 : acc11);
            int col = n0 + wn * 32 + nf * 16 + nlo;
            float bcol = (mode >= 1) ? bias[col] : 0.f;
            float gs = 1.f;
            if (mode == 2 && gvec) gs = gvec[col];
            #pragma unroll
            for (int r = 0; r < 4; r++) {
                int row = m0 + wm * 32 + mi * 16 + quad * 4 + r;
                if (row >= M) continue;
                float v = av[r] + bcol;
                if (mode == 1) v = 0.5f * v * (1.f + erff(v * 0.70710678118654752f));
                if (mode == 2) {
                    Cf[(size_t)row * Np + col] = resid[(size_t)row * Np + col] + gs * v;
                } else {
                    Cb[(size_t)row * Np + col] = f2bf(v);
                }
            }
        }
    }
}

// ------------------------------------------------------------------
// MFMA flash attention (no rel) v2: TWO-PASS softmax (verified R6).
// ------------------------------------------------------------------
__global__ __launch_bounds__(256) void attn_mfma_kernel(
        const short* __restrict__ qkv, const float* __restrict__ maskv,
        short* __restrict__ ob, int Nseq) {
    __shared__ short kf[18][64][8];
    __shared__ short vf[9][2][64][8];
    __shared__ short pbuf[4][2][16][40];
    __shared__ float ms[320];

    int tid = threadIdx.x;
    int w = tid >> 6, lane = tid & 63;
    int n = lane & 15, quad = lane >> 4;
    int qg = blockIdx.x, h = blockIdx.y, b = blockIdx.z;
    size_t rowB = (size_t)(b * Nseq);

    for (int j = tid; j < 320; j += 256)
        ms[j] = (j < Nseq) ? maskv[b * Nseq + j] : 0.f;

    {
        int c0 = (tid & 3) * 8;
        for (int j = tid >> 2; j < 288; j += 64) {
            frag8 kk = {0, 0, 0, 0, 0, 0, 0, 0};
            frag8 vv = {0, 0, 0, 0, 0, 0, 0, 0};
            if (j < Nseq) {
                const short* base = qkv + (rowB + j) * QP + h * HD + c0;
                kk = *(const frag8*)(base + 384);
                vv = *(const frag8*)(base + 768);
            }
            *(frag8*)&kf[j >> 4][(c0 >> 3) * 16 + (j & 15)][0] = kk;
            #pragma unroll
            for (int e = 0; e < 8; e++) {
                int c = c0 + e;
                vf[j >> 5][c >> 4][((j & 31) >> 3) * 16 + (c & 15)][j & 7] = vv[e];
            }
        }
    }

    int i0 = qg * 64 + w * 16;
    frag8 qa = {0, 0, 0, 0, 0, 0, 0, 0};
    {
        int i = i0 + n;
        if (i < Nseq) qa = *(const frag8*)(qkv + (rowB + i) * QP + h * HD + quad * 8);
    }
    __syncthreads();

    float msq[4];
    #pragma unroll
    for (int r = 0; r < 4; r++) msq[r] = ms[i0 + quad * 4 + r];

    // ---- pass 1: all 72 scores into registers, local row max ----
    float sv0[36], sv1[36];
    float rmax[4];
    #pragma unroll
    for (int r = 0; r < 4; r++) rmax[r] = -3.0e38f;

    #pragma unroll
    for (int jb = 0; jb < 9; jb++) {
        frag8 kb0 = *(const frag8*)&kf[2 * jb][lane][0];
        frag8 kb1 = *(const frag8*)&kf[2 * jb + 1][lane][0];
        f32x4 z = {0.f, 0.f, 0.f, 0.f};
        f32x4 s0 = __builtin_amdgcn_mfma_f32_16x16x32_bf16(qa, kb0, z, 0, 0, 0);
        f32x4 s1 = __builtin_amdgcn_mfma_f32_16x16x32_bf16(qa, kb1, z, 0, 0, 0);

        int j0 = jb * 32 + n;
        int j1 = j0 + 16;
        float mj0 = ms[j0], mj1 = ms[j1];
        float pad0 = (j0 < Nseq) ? 0.f : -1e9f;
        float pad1 = (j1 < Nseq) ? 0.f : -1e9f;

        #pragma unroll
        for (int r = 0; r < 4; r++) {
            float mi = msq[r];
            float b0 = ((fmaxf(mi, mj0) < 0.f) ? 0.f : fminf(mi, mj0)) + pad0;
            float b1 = ((fmaxf(mi, mj1) < 0.f) ? 0.f : fminf(mi, mj1)) + pad1;
            float v0 = s0[r] * SCALE + b0;
            float v1 = s1[r] * SCALE + b1;
            sv0[jb * 4 + r] = v0;
            sv1[jb * 4 + r] = v1;
            rmax[r] = fmaxf(rmax[r], fmaxf(v0, v1));
        }
    }
    #pragma unroll
    for (int r = 0; r < 4; r++) {
        float rm = rmax[r];
        rm = fmaxf(rm, __shfl_xor(rm, 1));
        rm = fmaxf(rm, __shfl_xor(rm, 2));
        rm = fmaxf(rm, __shfl_xor(rm, 4));
        rm = fmaxf(rm, __shfl_xor(rm, 8));
        rmax[r] = rm;
    }

    // ---- exp + row sum ----
    float lsum[4] = {0.f, 0.f, 0.f, 0.f};
    #pragma unroll
    for (int jb = 0; jb < 9; jb++) {
        #pragma unroll
        for (int r = 0; r < 4; r++) {
            float p0 = __expf(sv0[jb * 4 + r] - rmax[r]);
            float p1 = __expf(sv1[jb * 4 + r] - rmax[r]);
            sv0[jb * 4 + r] = p0;
            sv1[jb * 4 + r] = p1;
            lsum[r] += p0 + p1;
        }
    }
    float invl[4];
    #pragma unroll
    for (int r = 0; r < 4; r++) {
        float ls = lsum[r];
        ls += __shfl_xor(ls, 1);
        ls += __shfl_xor(ls, 2);
        ls += __shfl_xor(ls, 4);
        ls += __shfl_xor(ls, 8);
        invl[r] = 1.f / ls;
    }

    // ---- pass 2: normalized P -> LDS, PV MFMA ----
    f32x4 oacc0 = {0.f, 0.f, 0.f, 0.f}, oacc1 = {0.f, 0.f, 0.f, 0.f};
    #pragma unroll
    for (int jb = 0; jb < 9; jb++) {
        int par = jb & 1;
        #pragma unroll
        for (int r = 0; r < 4; r++) {
            pbuf[w][par][quad * 4 + r][n]      = f2bf(sv0[jb * 4 + r] * invl[r]);
            pbuf[w][par][quad * 4 + r][n + 16] = f2bf(sv1[jb * 4 + r] * invl[r]);
        }
        frag8 pa = *(const frag8*)&pbuf[w][par][n][quad * 8];
        frag8 vb0 = *(const frag8*)&vf[jb][0][lane][0];
        frag8 vb1 = *(const frag8*)&vf[jb][1][lane][0];
        oacc0 = __builtin_amdgcn_mfma_f32_16x16x32_bf16(pa, vb0, oacc0, 0, 0, 0);
        oacc1 = __builtin_amdgcn_mfma_f32_16x16x32_bf16(pa, vb1, oacc1, 0, 0, 0);
    }

    #pragma unroll
    for (int r = 0; r < 4; r++) {
        int i = i0 + quad * 4 + r;
        if (i < Nseq) {
            ob[(rowB + i) * DIM + h * HD + n]      = f2bf(oacc0[r]);
            ob[(rowB + i) * DIM + h * HD + 16 + n] = f2bf(oacc1[r]);
        }
    }
}

// ------------------------------------------------------------------
// MFMA flash attention WITH rel bias (layer 0).  Two-pass softmax,
// writes normalized P in-place to rs, main PV to f32 omain.
// ------------------------------------------------------------------
__global__ __launch_bounds__(128) void attn_rel_mfma_kernel(
        const short* __restrict__ qkv, short* __restrict__ rs,
        const float* __restrict__ maskv, float* __restrict__ omain) {
    const int Nseq = N1;
    __shared__ short kf[16][64][8];
    __shared__ short vf[8][2][64][8];
    __shared__ short pbuf[2][2][16][40];
    __shared__ float ms[256];

    int tid = threadIdx.x;
    int w = tid >> 6, lane = tid & 63;
    int n = lane & 15, quad = lane >> 4;
    int qg = blockIdx.x, h = blockIdx.y, b = blockIdx.z;
    size_t rowB = (size_t)(b * Nseq);

    for (int jj = tid; jj < 256; jj += 128) ms[jj] = maskv[b * Nseq + jj];

    {
        int c0 = (tid & 3) * 8;
        for (int j = tid >> 2; j < 256; j += 32) {
            const short* base = qkv + (rowB + j) * QP + h * HD + c0;
            frag8 kk = *(const frag8*)(base + 384);
            frag8 vv = *(const frag8*)(base + 768);
            *(frag8*)&kf[j >> 4][(c0 >> 3) * 16 + (j & 15)][0] = kk;
            #pragma unroll
            for (int e = 0; e < 8; e++) {
                int c = c0 + e;
                vf[j >> 5][c >> 4][((j & 31) >> 3) * 16 + (c & 15)][j & 7] = vv[e];
            }
        }
    }

    int i0 = qg * 32 + w * 16;
    frag8 qa = *(const frag8*)(qkv + (rowB + i0 + n) * QP + h * HD + quad * 8);
    __syncthreads();

    float msq[4];
    short* rsp[4];
    #pragma unroll
    for (int r = 0; r < 4; r++) {
        msq[r] = ms[i0 + quad * 4 + r];
        rsp[r] = rs + ((size_t)(b * HEADS + h) * N1 + (i0 + quad * 4 + r)) * N1;
    }

    float sv0[32], sv1[32];
    float rmax[4];
    #pragma unroll
    for (int r = 0; r < 4; r++) rmax[r] = -3.0e38f;

    #pragma unroll
    for (int jb = 0; jb < 8; jb++) {
        frag8 kb0 = *(const frag8*)&kf[2 * jb][lane][0];
        frag8 kb1 = *(const frag8*)&kf[2 * jb + 1][lane][0];
        f32x4 z = {0.f, 0.f, 0.f, 0.f};
        f32x4 s0 = __builtin_amdgcn_mfma_f32_16x16x32_bf16(qa, kb0, z, 0, 0, 0);
        f32x4 s1 = __builtin_amdgcn_mfma_f32_16x16x32_bf16(qa, kb1, z, 0, 0, 0);
        int j0 = jb * 32 + n;
        int j1 = j0 + 16;
        float mj0 = ms[j0], mj1 = ms[j1];
        #pragma unroll
        for (int r = 0; r < 4; r++) {
            float d0 = bf2f(rsp[r][j0]);
            float d1 = bf2f(rsp[r][j1]);
            float mi = msq[r];
            float b0 = (fmaxf(mi, mj0) < 0.f) ? 0.f : fminf(mi, mj0);
            float b1 = (fmaxf(mi, mj1) < 0.f) ? 0.f : fminf(mi, mj1);
            float v0 = s0[r] * SCALE + d0 + b0;
            float v1 = s1[r] * SCALE + d1 + b1;
            sv0[jb * 4 + r] = v0;
            sv1[jb * 4 + r] = v1;
            rmax[r] = fmaxf(rmax[r], fmaxf(v0, v1));
        }
    }
    #pragma unroll
    for (int r = 0; r < 4; r++) {
        float rm = rmax[r];
        rm = fmaxf(rm, __shfl_xor(rm, 1));
        rm = fmaxf(rm, __shfl_xor(rm, 2));
        rm = fmaxf(rm, __shfl_xor(rm, 4));
        rm = fmaxf(rm, __shfl_xor(rm, 8));
        rmax[r] = rm;
    }

    float lsum[4] = {0.f, 0.f, 0.f, 0.f};
    #pragma unroll
    for (int jb = 0; jb < 8; jb++) {
        #pragma unroll
        for (int r = 0; r < 4; r++) {
            float p0 = __expf(sv0[jb * 4 + r] - rmax[r]);
            float p1 = __expf(sv1[jb * 4 + r] - rmax[r]);
            sv0[jb * 4 + r] = p0;
            sv1[jb * 4 + r] = p1;
            lsum[r] += p0 + p1;
        }
    }
    float invl[4];
    #pragma unroll
    for (int r = 0; r < 4; r++) {
        float ls = lsum[r];
        ls += __shfl_xor(ls, 1);
        ls += __shfl_xor(ls, 2);
        ls += __shfl_xor(ls, 4);
        ls += __shfl_xor(ls, 8);
        invl[r] = 1.f / ls;
    }

    f32x4 oacc0 = {0.f, 0.f, 0.f, 0.f}, oacc1 = {0.f, 0.f, 0.f, 0.f};
    #pragma unroll
    for (int jb = 0; jb < 8; jb++) {
        int par = jb & 1;
        #pragma unroll
        for (int r = 0; r < 4; r++) {
            short h0 = f2bf(sv0[jb * 4 + r] * invl[r]);
            short h1 = f2bf(sv1[jb * 4 + r] * invl[r]);
            pbuf[w][par][quad * 4 + r][n]      = h0;
            pbuf[w][par][quad * 4 + r][n + 16] = h1;
            rsp[r][jb * 32 + n]      = h0;
            rsp[r][jb * 32 + n + 16] = h1;
        }
        frag8 pa = *(const frag8*)&pbuf[w][par][n][quad * 8];
        frag8 vb0 = *(const frag8*)&vf[jb][0][lane][0];
        frag8 vb1 = *(const frag8*)&vf[jb][1][lane][0];
        oacc0 = __builtin_amdgcn_mfma_f32_16x16x32_bf16(pa, vb0, oacc0, 0, 0, 0);
        oacc1 = __builtin_amdgcn_mfma_f32_16x16x32_bf16(pa, vb1, oacc1, 0, 0, 0);
    }

    #pragma unroll
    for (int r = 0; r < 4; r++) {
        int i = i0 + quad * 4 + r;
        omain[(rowB + i) * DIM + h * HD + n]      = oacc0[r];
        omain[(rowB + i) * DIM + h * HD + 16 + n] = oacc1[r];
    }
}

// ------------------------------------------------------------------
__global__ __launch_bounds__(256) void concat_kernel(
        const float* __restrict__ xa, const float* __restrict__ clsw,
        const float* __restrict__ mask, float* __restrict__ xb,
        float* __restrict__ m2) {
    int idx = blockIdx.x * 256 + threadIdx.x;
    const int total = BATCH * N2 * DIM;
    if (idx < total) {
        int c = idx % DIM;
        int tokb = idx / DIM;
        int p = tokb % N2, b = tokb / N2;
        xb[idx] = (p == 0) ? clsw[c] : xa[((size_t)(b * N1) + p - 1) * DIM + c];
    }
    if (idx < BATCH * N2) {
        int p = idx % N2, b = idx / N2;
        m2[idx] = (p == 0) ? 0.f : mask[b * N1 + p - 1];
    }
}

__global__ __launch_bounds__(64) void head_kernel(
        const float* __restrict__ xb, const float* __restrict__ ow,
        const float* __restrict__ obv, float* __restrict__ out) {
    int blk = blockIdx.x;
    int b = blk / 3, o = blk % 3;
    int lane = threadIdx.x;
    const float* xr = xb + (size_t)(b * N2) * DIM;
    const float* wr = ow + o * DIM;
    float s = 0.f;
    for (int c = lane; c < DIM; c += 64) s += xr[c] * wr[c];
    for (int off = 32; off; off >>= 1) s += __shfl_down(s, off, 64);
    if (!lane) out[blk] = s + obv[o];
}

// ------------------------------------------------------------------
extern "C" void kernel_launch(void* const* d_in, const int* in_sizes, int n_in,
                              void* d_out, int out_size, void* d_ws, size_t ws_size,
                              hipStream_t stream) {
    (void)in_sizes; (void)n_in; (void)out_size; (void)ws_size;
    const float* X       = (const float*)d_in[0];
    const float* X0      = (const float*)d_in[1];
    const float* MSK     = (const float*)d_in[2];
    const float* RW1     = (const float*)d_in[3];
    const float* RB1     = (const float*)d_in[4];
    const float* RWP     = (const float*)d_in[5];
    const float* RBP     = (const float*)d_in[6];
    const float* SW_LN1G = (const float*)d_in[7];
    const float* SW_LN1B = (const float*)d_in[8];
    const float* SW_LN2G = (const float*)d_in[9];
    const float* SW_LN2B = (const float*)d_in[10];
    const float* SW_WQ   = (const float*)d_in[11];
    const float* SW_WK   = (const float*)d_in[12];
    const float* SW_WV   = (const float*)d_in[13];
    const float* SW_WO   = (const float*)d_in[14];
    const float* SW_BO   = (const float*)d_in[15];
    const float* SW_W1   = (const float*)d_in[16];
    const float* SW_B1   = (const float*)d_in[17];
    const float* SW_W2   = (const float*)d_in[18];
    const float* SW_B2   = (const float*)d_in[19];
    const float* BL_LN1G = (const float*)d_in[20];
    const float* BL_LN1B = (const float*)d_in[21];
    const float* BL_LN2G = (const float*)d_in[22];
    const float* BL_LN2B = (const float*)d_in[23];
    const float* BL_WQ   = (const float*)d_in[24];
    const float* BL_WK   = (const float*)d_in[25];
    const float* BL_WV   = (const float*)d_in[26];
    const float* BL_WO   = (const float*)d_in[27];
    const float* BL_BO   = (const float*)d_in[28];
    const float* BL_W1   = (const float*)d_in[29];
    const float* BL_B1   = (const float*)d_in[30];
    const float* BL_W2   = (const float*)d_in[31];
    const float* BL_B2   = (const float*)d_in[32];
    const float* BL_G1   = (const float*)d_in[33];
    const float* BL_G2   = (const float*)d_in[34];
    const float* CLSW    = (const float*)d_in[35];
    const float* OUTW    = (const float*)d_in[36];
    const float* OUTB    = (const float*)d_in[37];

    const int T1 = BATCH * N1;   // 2048
    const int T2 = BATCH * N2;   // 2056
    const size_t RELSZ = (size_t)BATCH * N1 * N1 * HD;   // shorts

    short* rel = (short*)d_ws;
    float* xa  = (float*)(rel + RELSZ);
    float* xb  = xa + (size_t)T1 * DIM;
    float* m2  = xb + (size_t)T2 * DIM;
    short* sbase = (short*)(m2 + 2064);
    short* xn   = sbase;
    short* qkv  = xn  + (size_t)T2 * DIM;
    short* ab   = qkv + (size_t)T2 * QP;
    short* hb   = ab  + (size_t)T2 * DIM;
    short* cw_qkv_sw = hb + (size_t)T2 * MLP_H;
    short* cw_qkv_bl = cw_qkv_sw + (size_t)4  * QP * DIM;
    short* cw_wo_sw  = cw_qkv_bl + (size_t)12 * QP * DIM;
    short* cw_wo_bl  = cw_wo_sw  + (size_t)4  * DIM * DIM;
    short* cw_w1_sw  = cw_wo_bl  + (size_t)12 * DIM * DIM;
    short* cw_w1_bl  = cw_w1_sw  + (size_t)4  * MLP_H * DIM;
    short* cw_w2_sw  = cw_w1_bl  + (size_t)12 * MLP_H * DIM;
    short* cw_w2_bl  = cw_w2_sw  + (size_t)4  * DIM * MLP_H;
    short* rs_buf    = cw_w2_bl  + (size_t)12 * DIM * MLP_H;  // [B][H][N1][N1] bf16
    float* omain     = (float*)hb;   // f32 scratch for layer-0 main PV

    // ---- weight conversion ----
    conv_qkv_kernel<<<(4 * QP * DIM / 4 + 255) / 256, 256, 0, stream>>>(SW_WQ, SW_WK, SW_WV, cw_qkv_sw, 4);
    conv_qkv_kernel<<<(12 * QP * DIM / 4 + 255) / 256, 256, 0, stream>>>(BL_WQ, BL_WK, BL_WV, cw_qkv_bl, 12);
    {
        int e0 = 4 * DIM * DIM, e1 = 12 * DIM * DIM;
        int e2 = 4 * MLP_H * DIM, e3 = 12 * MLP_H * DIM;
        int e4 = 4 * DIM * MLP_H, e5 = 12 * DIM * MLP_H;
        int nblk = (e0 + e1 + e2 + e3 + e4 + e5) >> 10;
        conv6_kernel<<<nblk, 256, 0, stream>>>(
            SW_WO, cw_wo_sw, e0, BL_WO, cw_wo_bl, e1,
            SW_W1, cw_w1_sw, e2, BL_W1, cw_w1_bl, e3,
            SW_W2, cw_w2_sw, e4, BL_W2, cw_w2_bl, e5);
    }

    rel_kernel<<<BATCH * N1 * N1 / 256, 256, 0, stream>>>(X0, RW1, RB1, RWP, RBP, rel);
    hipMemcpyAsync(xa, X, sizeof(float) * T1 * DIM, hipMemcpyDeviceToDevice, stream);

    // ---------------- phase 1: sw layers (N=256) ----------------
    dim3 gQ1(QP / 64, T1 / 128);          // wide-tile: 128 M-rows
    dim3 gP1(DIM / 64, T1 / 64);
    dim3 gM1(MLP_H / 64, T1 / 128);
    dim3 gF1(4, HEADS, BATCH);
    dim3 gRel(8, HEADS, BATCH);
    for (int l = 0; l < 4; l++) {
        const short* wqkv = cw_qkv_sw + (size_t)l * QP * DIM;
        const short* wo = cw_wo_sw + (size_t)l * DIM * DIM;
        const short* w1 = cw_w1_sw + (size_t)l * MLP_H * DIM;
        const short* w2 = cw_w2_sw + (size_t)l * DIM * MLP_H;
        const float* bo = SW_BO + (size_t)l * DIM;
        const float* b1 = SW_B1 + (size_t)l * MLP_H;
        const float* b2 = SW_B2 + (size_t)l * DIM;

        ln_kernel<<<T1, 128, 0, stream>>>(xa, SW_LN1G + l * DIM, SW_LN1B + l * DIM, xn);
        gemm128_bf16_kernel<<<gQ1, 512, 0, stream>>>(xn, wqkv, nullptr, qkv,
                                                     T1, QP, DIM, 0);
        if (l == 0) {
            rel_score_kernel<<<dim3(N1 / 4, BATCH), 256, 0, stream>>>(qkv, rel, rs_buf);
            attn_rel_mfma_kernel<<<gRel, 128, 0, stream>>>(qkv, rs_buf, MSK, omain);
            rel_pv_kernel<<<dim3(N1 / 4, BATCH), 256, 0, stream>>>(rs_buf, rel, omain, ab);
        } else {
            attn_mfma_kernel<<<gF1, 256, 0, stream>>>(qkv, MSK, ab, N1);
        }
        gemm_bf16_kernel<<<gP1, 512, 0, stream>>>(ab, wo, bo, xa, nullptr,
                                                  xa, nullptr, T1, DIM, DIM, 2);
        ln_kernel<<<T1, 128, 0, stream>>>(xa, SW_LN2G + l * DIM, SW_LN2B + l * DIM, xn);
        gemm128_bf16_kernel<<<gM1, 512, 0, stream>>>(xn, w1, b1, hb,
                                                     T1, MLP_H, DIM, 1);
        gemm_bf16_kernel<<<gP1, 512, 0, stream>>>(hb, w2, b2, xa, nullptr,
                                                  xa, nullptr, T1, DIM, MLP_H, 2);
    }

    // ---------------- concat cls ----------------
    concat_kernel<<<(BATCH * N2 * DIM + 255) / 256, 256, 0, stream>>>(xa, CLSW, MSK, xb, m2);

    // ---------------- phase 2: bl layers (N=257) ----------------
    int MB2 = (T2 + 63) / 64;
    int MB2w = (T2 + 127) / 128;
    dim3 gQ2(QP / 64, MB2w);
    dim3 gP2(DIM / 64, MB2);
    dim3 gM2(MLP_H / 64, MB2w);
    dim3 gF2(5, HEADS, BATCH);
    for (int l = 0; l < 12; l++) {
        const short* wqkv = cw_qkv_bl + (size_t)l * QP * DIM;
        const short* wo = cw_wo_bl + (size_t)l * DIM * DIM;
        const short* w1 = cw_w1_bl + (size_t)l * MLP_H * DIM;
        const short* w2 = cw_w2_bl + (size_t)l * DIM * MLP_H;
        const float* bo = BL_BO + (size_t)l * DIM;
        const float* b1 = BL_B1 + (size_t)l * MLP_H;
        const float* b2 = BL_B2 + (size_t)l * DIM;
        const float* g1 = BL_G1 + (size_t)l * DIM;
        const float* g2 = BL_G2 + (size_t)l * DIM;

        ln_kernel<<<T2, 128, 0, stream>>>(xb, BL_LN1G + l * DIM, BL_LN1B + l * DIM, xn);
        gemm128_bf16_kernel<<<gQ2, 512, 0, stream>>>(xn, wqkv, nullptr, qkv,
                                                     T2, QP, DIM, 0);
        attn_mfma_kernel<<<gF2, 256, 0, stream>>>(qkv, m2, ab, N2);
        gemm_bf16_kernel<<<gP2, 512, 0, stream>>>(ab, wo, bo, xb, g1,
                                                  xb, nullptr, T2, DIM, DIM, 2);
        ln_kernel<<<T2, 128, 0, stream>>>(xb, BL_LN2G + l * DIM, BL_LN2B + l * DIM, xn);
        gemm128_bf16_kernel<<<gM2, 512, 0, stream>>>(xn, w1, b1, hb,
                                                     T2, MLP_H, DIM, 1);
        gemm_bf16_kernel<<<gP2, 512, 0, stream>>>(hb, w2, b2, xb, g2,
                                                  xb, nullptr, T2, DIM, MLP_H, 2);
    }

    // ---------------- head ----------------
    head_kernel<<<BATCH * 3, 64, 0, stream>>>(xb, OUTW, OUTB, (float*)d_out);
}